// Round 1
// 106.051 us; speedup vs baseline: 1.0569x; 1.0569x over previous
//
#include <hip/hip_runtime.h>
#include <math.h>

#define NN   8192
#define DIM  128
#define NE   262144
#define XU   64           // xtx MFMA units, 128 rows each
#define JCH  128
#define HBH  64           // histogram chunks (256-thr, 4096 edges)
#define HEB  (NE / HBH)
#define PBP  64           // placement chunks (256-thr, 4096 edges)
#define PEB  (NE / PBP)
#define GU   128          // GEMM units, 64 rows each
#define GR   64

typedef __attribute__((ext_vector_type(8))) short bf16x8;
typedef __attribute__((ext_vector_type(4))) float f32x4;

// bf16 via explicit bit math (this ROCm's __hip_bfloat16 lacks .data)
static __device__ __forceinline__ unsigned short f2bf(float f) {
  unsigned int u = __float_as_uint(f);
  return (unsigned short)((u + 0x7FFFu + ((u >> 16) & 1u)) >> 16);   // RNE
}
static __device__ __forceinline__ float bf2f(unsigned int h) {
  return __uint_as_float(h << 16);
}
static __device__ __forceinline__ unsigned int pk2(float a, float b) {
  return (unsigned int)f2bf(a) | ((unsigned int)f2bf(b) << 16);
}

// ==================== phase unit functions ====================

// xtx unit u (256 thr): M-partial over 128 rows via MFMA.
// D = A·B^T when both frags are k-consecutive rows -> stage X^T in LDS:
// XTs[d][j] = bf16(x[j][d]*rinv_j) (A), XTu[d][j] = bf16(x[j][d]) (B).
// XOR-swizzle (row&7)<<4 kills the stride-256B bank conflict (G4).
static __device__ void ph_xtx(int u, int tid, char* smem,
    const float* __restrict__ x, float* __restrict__ rinv,
    float* __restrict__ Mpart) {
  char* XTs = smem;             // 32768 B
  char* XTu = smem + 32768;     // 32768 B
  int j0 = u * JCH;
  int jl = tid >> 1, half = tid & 1;
  const float4* xr = (const float4*)(x + (size_t)(j0 + jl) * DIM + half * 64);
  float ss = 0.f;
  #pragma unroll
  for (int i = 0; i < 16; ++i) {
    float4 v = xr[i];
    ss += v.x * v.x + v.y * v.y + v.z * v.z + v.w * v.w;
  }
  ss += __shfl_xor(ss, 1);                 // partner thread = same row
  float rv = 1.0f / sqrtf(ss);
  if (half == 0) rinv[j0 + jl] = rv;
  // transpose-stage this thread's own row-half (rv already in-register)
  #pragma unroll
  for (int c4 = 0; c4 < 16; ++c4) {
    float4 v = xr[c4];
    #pragma unroll
    for (int i = 0; i < 4; ++i) {
      int d = half * 64 + c4 * 4 + i;
      float f = ((const float*)&v)[i];
      int off = d * 256 + ((jl * 2) ^ ((d & 7) << 4));
      *(unsigned short*)(XTs + off) = f2bf(f * rv);
      *(unsigned short*)(XTu + off) = f2bf(f);
    }
  }
  __syncthreads();

  int w = tid >> 6, lane = tid & 63;
  int l15 = lane & 15, g16 = (lane >> 4) * 16, swz = (lane & 7) << 4;
  f32x4 acc[2][8];
  #pragma unroll
  for (int dt = 0; dt < 2; ++dt)
    #pragma unroll
    for (int ct = 0; ct < 8; ++ct) acc[dt][ct] = (f32x4){0.f, 0.f, 0.f, 0.f};
  #pragma unroll
  for (int ks = 0; ks < 4; ++ks) {
    int ko = (ks * 64 + g16) ^ swz;
    bf16x8 a0 = *(const bf16x8*)(XTs + (w * 32 + l15) * 256 + ko);
    bf16x8 a1 = *(const bf16x8*)(XTs + (w * 32 + 16 + l15) * 256 + ko);
    #pragma unroll
    for (int ct = 0; ct < 8; ++ct) {
      bf16x8 b = *(const bf16x8*)(XTu + (ct * 16 + l15) * 256 + ko);
      acc[0][ct] = __builtin_amdgcn_mfma_f32_16x16x32_bf16(a0, b, acc[0][ct], 0, 0, 0);
      acc[1][ct] = __builtin_amdgcn_mfma_f32_16x16x32_bf16(a1, b, acc[1][ct], 0, 0, 0);
    }
  }
  float* o = Mpart + (size_t)u * (DIM * DIM);
  #pragma unroll
  for (int dt = 0; dt < 2; ++dt)
    #pragma unroll
    for (int ct = 0; ct < 8; ++ct)
      #pragma unroll
      for (int r = 0; r < 4; ++r) {
        int row = w * 32 + dt * 16 + (lane >> 4) * 4 + r;   // C/D: row=(l>>4)*4+reg
        int col = ct * 16 + l15;                            // C/D: col=l&15
        o[row * DIM + col] = acc[dt][ct][r];
      }
}

// hist chunk h (256 thr): LDS histogram; 1 global atomic per TOUCHED bin
static __device__ void ph_hist(int h, int tid, int* ldeg,
    const int* __restrict__ ei, int* __restrict__ gcnt, int* __restrict__ slot) {
  int4* lz = (int4*)ldeg;
  #pragma unroll
  for (int i = tid; i < NN / 4; i += 256) lz[i] = make_int4(0, 0, 0, 0);
  __syncthreads();
  int e0 = h * HEB + tid * 16;
  int4 c0 = *(const int4*)(ei + NE + e0);       // targets
  int4 c1 = *(const int4*)(ei + NE + e0 + 4);
  int4 c2 = *(const int4*)(ei + NE + e0 + 8);
  int4 c3 = *(const int4*)(ei + NE + e0 + 12);
  int r0  = atomicAdd(&ldeg[c0.x], 1);
  int r1  = atomicAdd(&ldeg[c0.y], 1);
  int r2  = atomicAdd(&ldeg[c0.z], 1);
  int r3  = atomicAdd(&ldeg[c0.w], 1);
  int r4  = atomicAdd(&ldeg[c1.x], 1);
  int r5  = atomicAdd(&ldeg[c1.y], 1);
  int r6  = atomicAdd(&ldeg[c1.z], 1);
  int r7  = atomicAdd(&ldeg[c1.w], 1);
  int r8  = atomicAdd(&ldeg[c2.x], 1);
  int r9  = atomicAdd(&ldeg[c2.y], 1);
  int r10 = atomicAdd(&ldeg[c2.z], 1);
  int r11 = atomicAdd(&ldeg[c2.w], 1);
  int r12 = atomicAdd(&ldeg[c3.x], 1);
  int r13 = atomicAdd(&ldeg[c3.y], 1);
  int r14 = atomicAdd(&ldeg[c3.z], 1);
  int r15 = atomicAdd(&ldeg[c3.w], 1);
  __syncthreads();
  int binb = tid * 32;
  #pragma unroll
  for (int i = 0; i < 8; ++i) {
    int4 v = *(int4*)&ldeg[binb + i * 4];
    if (v.x) ldeg[binb + i * 4 + 0] = atomicAdd(&gcnt[binb + i * 4 + 0], v.x);
    if (v.y) ldeg[binb + i * 4 + 1] = atomicAdd(&gcnt[binb + i * 4 + 1], v.y);
    if (v.z) ldeg[binb + i * 4 + 2] = atomicAdd(&gcnt[binb + i * 4 + 2], v.z);
    if (v.w) ldeg[binb + i * 4 + 3] = atomicAdd(&gcnt[binb + i * 4 + 3], v.w);
  }
  __syncthreads();
  int4 s0 = make_int4(ldeg[c0.x] + r0,  ldeg[c0.y] + r1,  ldeg[c0.z] + r2,  ldeg[c0.w] + r3);
  int4 s1 = make_int4(ldeg[c1.x] + r4,  ldeg[c1.y] + r5,  ldeg[c1.z] + r6,  ldeg[c1.w] + r7);
  int4 s2 = make_int4(ldeg[c2.x] + r8,  ldeg[c2.y] + r9,  ldeg[c2.z] + r10, ldeg[c2.w] + r11);
  int4 s3 = make_int4(ldeg[c3.x] + r12, ldeg[c3.y] + r13, ldeg[c3.z] + r14, ldeg[c3.w] + r15);
  *(int4*)(slot + e0)      = s0;
  *(int4*)(slot + e0 + 4)  = s1;
  *(int4*)(slot + e0 + 8)  = s2;
  *(int4*)(slot + e0 + 12) = s3;
}

// M-reduce unit u (256 thr): sum 64 partials for 64 entries, emit bf16 into Bg
// rows 128..255 (M is symmetric, so row-major entries are already B^T layout).
static __device__ void ph_mred(int u, int tid, float* smemf,
    const float* __restrict__ Mpart, unsigned short* __restrict__ Bg) {
  int j0 = u * 64;
  int jj = tid & 63, sub = tid >> 6;
  const float* mp = Mpart + (size_t)(sub * 16) * (DIM * DIM) + j0;
  float s = 0.f;
  #pragma unroll 4
  for (int k = 0; k < 16; ++k) s += mp[(size_t)k * (DIM * DIM) + jj];
  smemf[sub * 64 + jj] = s;
  __syncthreads();
  if (tid < 64) {
    float v = smemf[tid] + smemf[64 + tid] + smemf[128 + tid] + smemf[192 + tid];
    int flat = j0 + tid;
    int row = flat >> 7, col = flat & 127;
    Bg[(size_t)(128 + row) * DIM + col] = f2bf(v);
  }
}

// W-transpose block b (256 thr): Bg rows 0..127 = W^T in bf16.
static __device__ void ph_wt(int b, int tid, float* smemf,
    const float* __restrict__ W, unsigned short* __restrict__ Bg) {
  float4* dst = (float4*)smemf;
  const float4* src = (const float4*)(W + (size_t)b * 32 * DIM);
  #pragma unroll
  for (int i = 0; i < 4; ++i) dst[tid + 256 * i] = src[tid + 256 * i];  // 32x128 f32
  __syncthreads();
  int j = tid >> 1, kh = (tid & 1) * 16;
  uint4 p0, p1;
  p0.x = pk2(smemf[(kh + 0) * DIM + j],  smemf[(kh + 1) * DIM + j]);
  p0.y = pk2(smemf[(kh + 2) * DIM + j],  smemf[(kh + 3) * DIM + j]);
  p0.z = pk2(smemf[(kh + 4) * DIM + j],  smemf[(kh + 5) * DIM + j]);
  p0.w = pk2(smemf[(kh + 6) * DIM + j],  smemf[(kh + 7) * DIM + j]);
  p1.x = pk2(smemf[(kh + 8) * DIM + j],  smemf[(kh + 9) * DIM + j]);
  p1.y = pk2(smemf[(kh + 10) * DIM + j], smemf[(kh + 11) * DIM + j]);
  p1.z = pk2(smemf[(kh + 12) * DIM + j], smemf[(kh + 13) * DIM + j]);
  p1.w = pk2(smemf[(kh + 14) * DIM + j], smemf[(kh + 15) * DIM + j]);
  uint4* op = (uint4*)(Bg + (size_t)j * DIM + b * 32 + kh);
  op[0] = p0; op[1] = p1;
}

// scan (256 thr): offs = exclusive scan of gcnt (=deg-1); dis = rsqrt(deg)
static __device__ void ph_scan(int tid, int* wsum,
    const int* __restrict__ gcnt, int* __restrict__ offs, float* __restrict__ dis) {
  int lane = tid & 63, wave = tid >> 6;
  const int4* g4 = (const int4*)gcnt;
  int s = 0;
  #pragma unroll
  for (int i = 0; i < 8; ++i) { int4 v = g4[tid * 8 + i]; s += v.x + v.y + v.z + v.w; }
  int sc = s;
  #pragma unroll
  for (int off = 1; off < 64; off <<= 1) {
    int v = __shfl_up(sc, off);
    if (lane >= off) sc += v;
  }
  if (lane == 63) wsum[wave] = sc;
  __syncthreads();
  if (wave == 0 && lane < 4) {
    int v = wsum[lane];
    #pragma unroll
    for (int off = 1; off < 4; off <<= 1) {
      int u = __shfl_up(v, off);
      if (lane >= off) v += u;
    }
    wsum[lane] = v;
  }
  __syncthreads();
  int run = (wave ? wsum[wave - 1] : 0) + sc - s;
  #pragma unroll
  for (int i = 0; i < 8; ++i) {
    int4 v = g4[tid * 8 + i];
    int4 o;
    o.x = run; run += v.x;
    o.y = run; run += v.y;
    o.z = run; run += v.z;
    o.w = run; run += v.w;
    *(int4*)&offs[tid * 32 + i * 4] = o;
    float4 d;
    d.x = rsqrtf((float)(v.x + 1)); d.y = rsqrtf((float)(v.y + 1));
    d.z = rsqrtf((float)(v.z + 1)); d.w = rsqrtf((float)(v.w + 1));
    *(float4*)&dis[tid * 32 + i * 4] = d;
  }
}

// GEMM unit u (256 thr, MFMA): rows [u*64, u*64+64), cols 0..255 of [W^T;M].
// x staged bf16-swizzled in LDS; B held entirely in registers (16 frags/wave,
// L2-resident 64 KB). Wave w owns cols [w*64, w*64+64); w<2 -> xw, w>=2 -> att.
static __device__ void ph_gemm(int u, int tid, char* smem,
    const float* __restrict__ x, const unsigned short* __restrict__ Bg,
    const float* __restrict__ rinv, const float* __restrict__ dis,
    unsigned short* __restrict__ xws, float* __restrict__ att) {
  char* A = smem;                         // 64 rows * 256 B = 16384
  float* rvs = (float*)(smem + 16384);    // 64
  float* dss = rvs + 64;                  // 64
  int row0 = u * GR;
  #pragma unroll
  for (int i = 0; i < 4; ++i) {
    int c = tid + 256 * i;                // 16B chunk 0..1023
    int row = c >> 4, kc = c & 15;
    const float4* s = (const float4*)(x + (size_t)(row0 + row) * DIM + kc * 8);
    float4 v0 = s[0], v1 = s[1];
    uint4 p;
    p.x = pk2(v0.x, v0.y); p.y = pk2(v0.z, v0.w);
    p.z = pk2(v1.x, v1.y); p.w = pk2(v1.z, v1.w);
    *(uint4*)(A + row * 256 + ((kc * 16) ^ ((row & 7) << 4))) = p;
  }
  if (tid < 64) { rvs[tid] = rinv[row0 + tid]; dss[tid] = dis[row0 + tid]; }

  int w = tid >> 6, lane = tid & 63;
  int l15 = lane & 15, g16 = (lane >> 4) * 16, swz = (lane & 7) << 4;
  bf16x8 breg[4][4];
  const char* Bgb = (const char*)Bg;
  #pragma unroll
  for (int ct = 0; ct < 4; ++ct) {
    int j = w * 64 + ct * 16 + l15;
    #pragma unroll
    for (int ks = 0; ks < 4; ++ks)
      breg[ct][ks] = *(const bf16x8*)(Bgb + j * 256 + ks * 64 + g16);
  }
  __syncthreads();

  f32x4 acc[4][4];
  #pragma unroll
  for (int rt = 0; rt < 4; ++rt)
    #pragma unroll
    for (int ct = 0; ct < 4; ++ct) acc[rt][ct] = (f32x4){0.f, 0.f, 0.f, 0.f};
  #pragma unroll
  for (int rt = 0; rt < 4; ++rt) {
    #pragma unroll
    for (int ks = 0; ks < 4; ++ks) {
      bf16x8 a = *(const bf16x8*)(A + (rt * 16 + l15) * 256 + ((ks * 64 + g16) ^ swz));
      #pragma unroll
      for (int ct = 0; ct < 4; ++ct)
        acc[rt][ct] = __builtin_amdgcn_mfma_f32_16x16x32_bf16(a, breg[ct][ks], acc[rt][ct], 0, 0, 0);
    }
  }

  bool isW = (w < 2);
  #pragma unroll
  for (int rt = 0; rt < 4; ++rt)
    #pragma unroll
    for (int ct = 0; ct < 4; ++ct)
      #pragma unroll
      for (int r = 0; r < 4; ++r) {
        int rl = rt * 16 + (lane >> 4) * 4 + r;
        int row = row0 + rl;
        int col = w * 64 + ct * 16 + l15;
        float v = acc[rt][ct][r];
        if (isW) {
          xws[(size_t)row * DIM + col] = f2bf(v * dss[rl]);
        } else {
          float gv = 1.0f / (1.0f + __expf(-v * rvs[rl]));
          att[(size_t)row * DIM + (col - 128)] = gv;
        }
      }
}

// placement chunk u (256 thr): pos = offs[tgt] + slot  (no atomics)
static __device__ void ph_place(int u, int tid,
    const int* __restrict__ ei, const int* __restrict__ offs,
    const int* __restrict__ slot, int* __restrict__ sorted) {
  int e0 = u * PEB + tid * 16;
  #pragma unroll
  for (int i = 0; i < 4; ++i) {
    int4 sv = *(const int4*)(ei + e0 + i * 4);          // sources
    int4 cv = *(const int4*)(ei + NE + e0 + i * 4);     // targets
    int4 sl = *(const int4*)(slot + e0 + i * 4);
    sorted[offs[cv.x] + sl.x] = sv.x;
    sorted[offs[cv.y] + sl.y] = sv.y;
    sorted[offs[cv.z] + sl.z] = sv.z;
    sorted[offs[cv.w] + sl.w] = sv.w;
  }
}

// ==================== kernels ====================
__global__ __launch_bounds__(256) void k_pA(const float* __restrict__ x,
    const int* __restrict__ ei, float* __restrict__ rinv,
    float* __restrict__ Mpart, int* __restrict__ gcnt, int* __restrict__ slot) {
  __shared__ float smem[16512];           // 66048 B: XTs+XTu (xtx) / ldeg (hist)
  int u = blockIdx.x, tid = threadIdx.x;
  if (u < XU) ph_xtx(u, tid, (char*)smem, x, rinv, Mpart);
  else        ph_hist(u - XU, tid, (int*)smem, ei, gcnt, slot);
}
__global__ __launch_bounds__(256) void k_pB(const float* __restrict__ Mpart,
    const float* __restrict__ W, unsigned short* __restrict__ Bg,
    const int* __restrict__ gcnt, int* __restrict__ offs, float* __restrict__ dis) {
  __shared__ float smem[4224];
  int u = blockIdx.x, tid = threadIdx.x;
  if (u < 256)      ph_mred(u, tid, smem, Mpart, Bg);
  else if (u == 256) ph_scan(tid, (int*)smem, gcnt, offs, dis);
  else              ph_wt(u - 257, tid, smem, W, Bg);
}
__global__ __launch_bounds__(256) void k_pC(const float* __restrict__ x,
    const unsigned short* __restrict__ Bg, const float* __restrict__ rinv,
    const float* __restrict__ dis, const int* __restrict__ ei,
    const int* __restrict__ offs, const int* __restrict__ slot,
    int* __restrict__ sorted, unsigned short* __restrict__ xws,
    float* __restrict__ att) {
  __shared__ float smem[4224];            // 16896 B: A tile + rvs/dss
  int u = blockIdx.x, tid = threadIdx.x;
  if (u < GU) ph_gemm(u, tid, (char*)smem, x, Bg, rinv, dis, xws, att);
  else        ph_place(u - GU, tid, ei, offs, slot, sorted);
}
// gather: one node per 64-thread wave-block; uint (ushort2) loads; unroll 8
__global__ __launch_bounds__(64) void k_pD(const int* __restrict__ offs,
    const int* __restrict__ gcnt, const float* __restrict__ dis,
    const unsigned short* __restrict__ xws, const float* __restrict__ att,
    const float* __restrict__ bias, const int* __restrict__ sorted,
    float* __restrict__ out) {
  int c = blockIdx.x, t = threadIdx.x;
  int base = offs[c];
  int cnt  = gcnt[c];                            // deg-1
  const unsigned int* xw2 = (const unsigned int*)xws;
  unsigned int sv = xw2[(size_t)c * 64 + t];     // self-loop term
  float acc0 = bf2f(sv & 0xffffu), acc1 = bf2f(sv >> 16);
  int k = 0;
  for (; k + 8 <= cnt; k += 8) {
    int4 i0 = *(const int4*)(sorted + base + k);
    int4 i1 = *(const int4*)(sorted + base + k + 4);
    unsigned int v0 = xw2[(size_t)i0.x * 64 + t];
    unsigned int v1 = xw2[(size_t)i0.y * 64 + t];
    unsigned int v2 = xw2[(size_t)i0.z * 64 + t];
    unsigned int v3 = xw2[(size_t)i0.w * 64 + t];
    unsigned int v4 = xw2[(size_t)i1.x * 64 + t];
    unsigned int v5 = xw2[(size_t)i1.y * 64 + t];
    unsigned int v6 = xw2[(size_t)i1.z * 64 + t];
    unsigned int v7 = xw2[(size_t)i1.w * 64 + t];
    acc0 += bf2f(v0 & 0xffffu) + bf2f(v1 & 0xffffu) + bf2f(v2 & 0xffffu) + bf2f(v3 & 0xffffu)
          + bf2f(v4 & 0xffffu) + bf2f(v5 & 0xffffu) + bf2f(v6 & 0xffffu) + bf2f(v7 & 0xffffu);
    acc1 += bf2f(v0 >> 16) + bf2f(v1 >> 16) + bf2f(v2 >> 16) + bf2f(v3 >> 16)
          + bf2f(v4 >> 16) + bf2f(v5 >> 16) + bf2f(v6 >> 16) + bf2f(v7 >> 16);
  }
  for (; k + 4 <= cnt; k += 4) {
    int4 i0 = *(const int4*)(sorted + base + k);
    unsigned int v0 = xw2[(size_t)i0.x * 64 + t];
    unsigned int v1 = xw2[(size_t)i0.y * 64 + t];
    unsigned int v2 = xw2[(size_t)i0.z * 64 + t];
    unsigned int v3 = xw2[(size_t)i0.w * 64 + t];
    acc0 += bf2f(v0 & 0xffffu) + bf2f(v1 & 0xffffu) + bf2f(v2 & 0xffffu) + bf2f(v3 & 0xffffu);
    acc1 += bf2f(v0 >> 16) + bf2f(v1 >> 16) + bf2f(v2 >> 16) + bf2f(v3 >> 16);
  }
  for (; k < cnt; ++k) {
    unsigned int v = xw2[(size_t)sorted[base + k] * 64 + t];
    acc0 += bf2f(v & 0xffffu);
    acc1 += bf2f(v >> 16);
  }
  float dc = dis[c];
  float2 at = ((const float2*)att)[(size_t)c * 64 + t];
  float2 bs = ((const float2*)bias)[t];
  float2 o;
  o.x = (acc0 * dc + bs.x) * at.x;
  o.y = (acc1 * dc + bs.y) * at.y;
  ((float2*)out)[(size_t)c * 64 + t] = o;
}

// ---------------------------------------------------------------------- launch
extern "C" void kernel_launch(void* const* d_in, const int* in_sizes, int n_in,
                              void* d_out, int out_size, void* d_ws, size_t ws_size,
                              hipStream_t stream) {
  const float* x  = (const float*)d_in[0];
  const int*   ei = (const int*)  d_in[1];
  const float* W  = (const float*)d_in[2];
  const float* b  = (const float*)d_in[3];
  float* out = (float*)d_out;

  // ws layout (~12.3 MB)
  unsigned short* xws = (unsigned short*)d_ws;            // NN*DIM bf16
  float* att   = (float*)(xws + (size_t)NN * DIM);        // NN*DIM f32
  unsigned short* Bg = (unsigned short*)(att + (size_t)NN * DIM); // 256*128 bf16
  float* Mpart = (float*)(Bg + 256 * DIM);                // XU*DIM*DIM (4 MB)
  float* rinv  = Mpart + (size_t)XU * DIM * DIM;          // NN
  float* dis   = rinv + NN;                               // NN
  int*   gcnt  = (int*)(dis + NN);                        // NN (zeroed below)
  int*   offs  = gcnt + NN;                               // NN
  int*   slot  = offs + NN;                               // NE
  int*   sorted= slot + NE;                               // NE

  hipMemsetAsync(gcnt, 0, NN * sizeof(int), stream);

  k_pA<<<XU + HBH, 256, 0, stream>>>(x, ei, rinv, Mpart, gcnt, slot);
  k_pB<<<261, 256, 0, stream>>>(Mpart, W, Bg, gcnt, offs, dis);
  k_pC<<<GU + PBP, 256, 0, stream>>>(x, Bg, rinv, dis, ei, offs, slot, sorted,
                                     xws, att);
  k_pD<<<NN, 64, 0, stream>>>(offs, gcnt, dis, xws, att, b, sorted, out);
}